// Round 5
// baseline (193.480 us; speedup 1.0000x reference)
//
#include <hip/hip_runtime.h>
#include <cstdint>
#include <cstddef>

#define N_DIM 1024
#define D_DIM 512
#define M_DIM 65536
#define NC 6

typedef float f32x4 __attribute__((ext_vector_type(4)));
typedef __bf16 bf16x8 __attribute__((ext_vector_type(8)));

__device__ __forceinline__ float sp_f(float z) {
    return z > 20.f ? z : log1pf(expf(z));
}

// ---------------- pack: bf16 weights, folded CW, normalized centroids, scalars,
// ---------------- + ortho loss (block 193) ----------------
__global__ void k_pack(const float* __restrict__ pw, const float* __restrict__ ciw,
                       const float* __restrict__ cow, const float* __restrict__ cent,
                       const float* __restrict__ ga, const float* __restrict__ rlt,
                       const float* __restrict__ sev,
                       __bf16* __restrict__ bpa, __bf16* __restrict__ bpl,
                       __bf16* __restrict__ w3p,
                       float* __restrict__ kn, float* __restrict__ cw,
                       float* __restrict__ scal, float* __restrict__ out_ortho) {
    __shared__ float skn[NC * 32];
    __shared__ float ssq[36];
    int bid = blockIdx.x, tid = threadIdx.x;
    if (bid < 128) {
        int i = bid * 256 + tid;          // 0..32767
        int c = i >> 9, k = i & 511;
        float w = (c < 32) ? pw[c * 512 + k] : ciw[(c - 32) * 544 + k];
        __bf16 hi = (__bf16)w;
        bpa[i] = hi;
        if (c < 32) bpl[i] = (__bf16)(w - (float)hi);
    } else if (bid < 192) {
        int j = (bid - 128) * 256 + tid;  // 0..16383
        w3p[j] = (__bf16)cow[j];
    } else if (bid == 192) {
        if (tid < 192) {                  // CW[k][h] = sum_p cent[k][p]*ciw[h][512+p]
            int k = tid >> 5, h = tid & 31;
            float s = 0.f;
            for (int p = 0; p < 32; ++p) s += cent[k * 32 + p] * ciw[h * 544 + 512 + p];
            cw[k * 32 + h] = s;
        } else if (tid < 192 + NC) {
            int k = tid - 192;
            float s = 0.f;
            for (int p = 0; p < 32; ++p) { float v = cent[k * 32 + p]; s += v * v; }
            float inv = 1.f / fmaxf(sqrtf(s), 1e-12f);
            for (int p = 0; p < 32; ++p) kn[k * 32 + p] = cent[k * 32 + p] * inv;
        } else if (tid == 198) {
            scal[0] = expf(rlt[0]);
            scal[1] = sp_f(sev[0]);
            scal[2] = 1.f / (1.f + expf(-ga[0]));
        }
    } else { // bid == 193: ortho loss
        if (tid < NC) {
            float s = 0.f;
            for (int p = 0; p < 32; ++p) { float v = cent[tid * 32 + p]; s += v * v; }
            float inv = 1.f / fmaxf(sqrtf(s), 1e-12f);
            for (int p = 0; p < 32; ++p) skn[tid * 32 + p] = cent[tid * 32 + p] * inv;
        }
        __syncthreads();
        if (tid < 36) {
            int i = tid / 6, j = tid % 6;
            float g = 0.f;
            for (int p = 0; p < 32; ++p) g += skn[i * 32 + p] * skn[j * 32 + p];
            float d = g - (i == j ? 1.f : 0.f);
            ssq[tid] = d * d;
        }
        __syncthreads();
        if (tid == 0) {
            float s = 0.f;
            for (int i = 0; i < 36; ++i) s += ssq[i];
            *out_ortho = s / 36.f;
        }
    }
}

// ---------------- stats pass 1: float4 partials ----------------
// grid 2048 x 128 threads; block = 32 rows x 512 cols
__global__ void k_stat1(const float* __restrict__ x, float* __restrict__ part) {
    int bid = blockIdx.x;
    int b = bid >> 5, sub = bid & 31;
    int d4 = threadIdx.x * 4;
    const float* px = x + ((size_t)(b * 1024 + sub * 32)) * 512 + d4;
    f32x4 s = {0.f, 0.f, 0.f, 0.f}, q = s;
    #pragma unroll 4
    for (int i = 0; i < 32; ++i) {
        float4 v = *(const float4*)(px + (size_t)i * 512);
        s.x += v.x; s.y += v.y; s.z += v.z; s.w += v.w;
        q.x += v.x * v.x; q.y += v.y * v.y; q.z += v.z * v.z; q.w += v.w * v.w;
    }
    *(f32x4*)(part + (size_t)bid * 512 + d4) = s;
    *(f32x4*)(part + (size_t)(2048 + bid) * 512 + d4) = q;
}

// ---------------- stats pass 2 ----------------
__global__ void k_stat2(const float* __restrict__ part, float* __restrict__ mean,
                        float* __restrict__ istd, float* __restrict__ stdv) {
    int b = blockIdx.x, d = threadIdx.x;
    float s = 0.f, q = 0.f;
    for (int c = 0; c < 32; ++c) {
        s += part[(size_t)(b * 32 + c) * 512 + d];
        q += part[(size_t)(2048 + b * 32 + c) * 512 + d];
    }
    float mu = s * (1.f / (float)N_DIM);
    float var = fmaxf((q - s * mu) * (1.f / (float)(N_DIM - 1)), 0.f);
    float sd = sqrtf(var) + 1e-5f;
    mean[b * D_DIM + d] = mu;
    istd[b * D_DIM + d] = 1.f / sd;
    stdv[b * D_DIM + d] = sd;
}

// ---------------- MEGA: split-K wave pairs, 32 rows/block ----------------
__launch_bounds__(256, 8)
__global__ void mega(const float* __restrict__ x,
                     const float* __restrict__ proj_b, const float* __restrict__ ln_g,
                     const float* __restrict__ ln_b, const float* __restrict__ cib,
                     const float* __restrict__ cob,
                     const float* __restrict__ mean, const float* __restrict__ istd,
                     const float* __restrict__ stdv,
                     const float* __restrict__ kn, const float* __restrict__ cw,
                     const float* __restrict__ scal,
                     const __bf16* __restrict__ bpa, const __bf16* __restrict__ bpl,
                     const __bf16* __restrict__ w3p,
                     float* __restrict__ out, float* __restrict__ ustd_out,
                     float* __restrict__ rout_part) {
    __shared__ float s_mean[512];
    __shared__ float s_is[512];
    __shared__ float s_sd[512];
    __shared__ float s_cob[512];
    __shared__ __align__(16) float s_tile[2][16][68];
    __shared__ __align__(16) __bf16 s_h[2][16][40];

    int tid = threadIdx.x;
    int wv = tid >> 6, ln = tid & 63;
    int l15 = ln & 15, lg = ln >> 4;
    int pair = wv >> 1, h = wv & 1;

    int b = blockIdx.x >> 5;            // 32 blocks per batch entry
    int wrow = blockIdx.x * 32 + pair * 16;

    // stage per-b vectors in LDS
    if (tid < 128) {
        *(float4*)&s_mean[tid * 4] = *(const float4*)(mean + b * 512 + tid * 4);
        *(float4*)&s_sd[tid * 4]   = *(const float4*)(stdv + b * 512 + tid * 4);
    } else {
        int t = tid - 128;
        *(float4*)&s_is[t * 4]  = *(const float4*)(istd + b * 512 + t * 4);
        *(float4*)&s_cob[t * 4] = *(const float4*)(cob + t * 4);
    }
    __syncthreads();

    int kbase = h * 256;
    const float* xr = x + (size_t)(wrow + l15) * 512 + kbase;
    const __bf16* w0  = bpa + (size_t)l15 * 512 + kbase;
    const __bf16* w1  = bpa + (size_t)(16 + l15) * 512 + kbase;
    const __bf16* w2  = bpa + (size_t)(32 + l15) * 512 + kbase;
    const __bf16* w3  = bpa + (size_t)(48 + l15) * 512 + kbase;
    const __bf16* wl0 = bpl + (size_t)l15 * 512 + kbase;
    const __bf16* wl1 = bpl + (size_t)(16 + l15) * 512 + kbase;

    // ---- Phase A (half-K per wave): C[16x64] partial
    f32x4 a0 = {0.f, 0.f, 0.f, 0.f}, a1 = a0, a2 = a0, a3 = a0;
    #pragma unroll 4
    for (int ks = 0; ks < 8; ++ks) {
        int k0 = ks * 32 + lg * 8;
        int kk = kbase + k0;
        float4 xa = *(const float4*)(xr + k0);
        float4 xb = *(const float4*)(xr + k0 + 4);
        float4 ma = *(const float4*)&s_mean[kk];
        float4 m2 = *(const float4*)&s_mean[kk + 4];
        float4 ia = *(const float4*)&s_is[kk];
        float4 i2 = *(const float4*)&s_is[kk + 4];
        float xnf[8];
        xnf[0] = (xa.x - ma.x) * ia.x; xnf[1] = (xa.y - ma.y) * ia.y;
        xnf[2] = (xa.z - ma.z) * ia.z; xnf[3] = (xa.w - ma.w) * ia.w;
        xnf[4] = (xb.x - m2.x) * i2.x; xnf[5] = (xb.y - m2.y) * i2.y;
        xnf[6] = (xb.z - m2.z) * i2.z; xnf[7] = (xb.w - m2.w) * i2.w;
        bf16x8 ah, al;
        #pragma unroll
        for (int j = 0; j < 8; ++j) {
            __bf16 hh = (__bf16)xnf[j];
            ah[j] = hh;
            al[j] = (__bf16)(xnf[j] - (float)hh);
        }
        bf16x8 wh0 = *(const bf16x8*)(w0 + k0);
        bf16x8 wh1 = *(const bf16x8*)(w1 + k0);
        a0 = __builtin_amdgcn_mfma_f32_16x16x32_bf16(ah, wh0, a0, 0, 0, 0);
        a0 = __builtin_amdgcn_mfma_f32_16x16x32_bf16(ah, *(const bf16x8*)(wl0 + k0), a0, 0, 0, 0);
        a0 = __builtin_amdgcn_mfma_f32_16x16x32_bf16(al, wh0, a0, 0, 0, 0);
        a1 = __builtin_amdgcn_mfma_f32_16x16x32_bf16(ah, wh1, a1, 0, 0, 0);
        a1 = __builtin_amdgcn_mfma_f32_16x16x32_bf16(ah, *(const bf16x8*)(wl1 + k0), a1, 0, 0, 0);
        a1 = __builtin_amdgcn_mfma_f32_16x16x32_bf16(al, wh1, a1, 0, 0, 0);
        a2 = __builtin_amdgcn_mfma_f32_16x16x32_bf16(ah, *(const bf16x8*)(w2 + k0), a2, 0, 0, 0);
        a3 = __builtin_amdgcn_mfma_f32_16x16x32_bf16(ah, *(const bf16x8*)(w3 + k0), a3, 0, 0, 0);
    }

    // h=1 publishes partials
    if (h == 1) {
        #pragma unroll
        for (int rg = 0; rg < 4; ++rg) {
            int row = lg * 4 + rg;
            s_tile[pair][row][l15]      = a0[rg];
            s_tile[pair][row][16 + l15] = a1[rg];
            s_tile[pair][row][32 + l15] = a2[rg];
            s_tile[pair][row][48 + l15] = a3[rg];
        }
    }
    __syncthreads();

    // h=0 combines and runs row ops (same-wave DS ordering covers write->read)
    if (h == 0) {
        #pragma unroll
        for (int rg = 0; rg < 4; ++rg) {
            int row = lg * 4 + rg;
            s_tile[pair][row][l15]      += a0[rg];
            s_tile[pair][row][16 + l15] += a1[rg];
            s_tile[pair][row][32 + l15] += a2[rg];
            s_tile[pair][row][48 + l15] += a3[rg];
        }

        int r = ln >> 2, sub = ln & 3;
        const float* tr = &s_tile[pair][r][0];
        float4 t0 = *(const float4*)(tr + sub * 8);
        float4 t1 = *(const float4*)(tr + sub * 8 + 4);
        float4 pb0 = *(const float4*)(proj_b + sub * 8);
        float4 pb1 = *(const float4*)(proj_b + sub * 8 + 4);
        float P[8];
        P[0] = t0.x + pb0.x; P[1] = t0.y + pb0.y; P[2] = t0.z + pb0.z; P[3] = t0.w + pb0.w;
        P[4] = t1.x + pb1.x; P[5] = t1.y + pb1.y; P[6] = t1.z + pb1.z; P[7] = t1.w + pb1.w;
        float m = 0.f;
        #pragma unroll
        for (int j = 0; j < 8; ++j) m += P[j];
        m += __shfl_xor(m, 1); m += __shfl_xor(m, 2);
        float mu = m * (1.f / 32.f);
        float v = 0.f;
        #pragma unroll
        for (int j = 0; j < 8; ++j) { float d = P[j] - mu; v += d * d; }
        v += __shfl_xor(v, 1); v += __shfl_xor(v, 2);
        float rs = rsqrtf(v * (1.f / 32.f) + 1e-5f);
        float4 g0 = *(const float4*)(ln_g + sub * 8);
        float4 g1 = *(const float4*)(ln_g + sub * 8 + 4);
        float4 bl0 = *(const float4*)(ln_b + sub * 8);
        float4 bl1 = *(const float4*)(ln_b + sub * 8 + 4);
        float gg[8] = {g0.x, g0.y, g0.z, g0.w, g1.x, g1.y, g1.z, g1.w};
        float bb[8] = {bl0.x, bl0.y, bl0.z, bl0.w, bl1.x, bl1.y, bl1.z, bl1.w};
        float q[8]; float n2 = 0.f;
        #pragma unroll
        for (int j = 0; j < 8; ++j) {
            q[j] = (P[j] - mu) * rs * gg[j] + bb[j];
            n2 += q[j] * q[j];
        }
        n2 += __shfl_xor(n2, 1); n2 += __shfl_xor(n2, 2);
        float inv = 1.f / fmaxf(sqrtf(n2), 1e-12f);
        float sim[6];
        #pragma unroll
        for (int k = 0; k < 6; ++k) {
            const float* kr = kn + k * 32 + sub * 8;
            float4 ka = *(const float4*)(kr);
            float4 kb = *(const float4*)(kr + 4);
            float s = q[0] * ka.x + q[1] * ka.y + q[2] * ka.z + q[3] * ka.w
                    + q[4] * kb.x + q[5] * kb.y + q[6] * kb.z + q[7] * kb.w;
            s += __shfl_xor(s, 1); s += __shfl_xor(s, 2);
            sim[k] = s * inv;
        }
        float T = scal[0], sevv = scal[1];
        float mx = sim[0];
        #pragma unroll
        for (int k = 1; k < 6; ++k) mx = fmaxf(mx, sim[k]);
        float e[6], es = 0.f;
        #pragma unroll
        for (int k = 0; k < 6; ++k) { e[k] = expf((sim[k] - mx) * T); es += e[k]; }
        float einv = 1.f / es;
        float a[6];
        #pragma unroll
        for (int k = 0; k < 6; ++k) a[k] = e[k] * einv;
        float msim = 0.f;
        #pragma unroll
        for (int k = 0; k < 6; ++k) msim += sim[k];
        msim *= (1.f / 6.f);
        float S = 6.f;
        #pragma unroll
        for (int k = 0; k < 6; ++k) S += sevv * sp_f((sim[k] - msim) * 5.f);
        if (sub == 0) ustd_out[wrow + r] = 6.f / S;
        // h = gelu(corr_pre + cib + sum_k a_k*CW[k][:])
        float4 h0 = *(const float4*)(tr + 32 + sub * 8);
        float4 h1 = *(const float4*)(tr + 32 + sub * 8 + 4);
        float4 c0 = *(const float4*)(cib + sub * 8);
        float4 c1 = *(const float4*)(cib + sub * 8 + 4);
        float vh[8] = {h0.x + c0.x, h0.y + c0.y, h0.z + c0.z, h0.w + c0.w,
                       h1.x + c1.x, h1.y + c1.y, h1.z + c1.z, h1.w + c1.w};
        #pragma unroll
        for (int k = 0; k < 6; ++k) {
            const float* cr = cw + k * 32 + sub * 8;
            float4 ca = *(const float4*)(cr);
            float4 cb = *(const float4*)(cr + 4);
            vh[0] += a[k] * ca.x; vh[1] += a[k] * ca.y; vh[2] += a[k] * ca.z; vh[3] += a[k] * ca.w;
            vh[4] += a[k] * cb.x; vh[5] += a[k] * cb.y; vh[6] += a[k] * cb.z; vh[7] += a[k] * cb.w;
        }
        bf16x8 hv;
        #pragma unroll
        for (int j = 0; j < 8; ++j) {
            float gv = 0.5f * vh[j] * (1.f + erff(vh[j] * 0.70710678118654752f));
            hv[j] = (__bf16)gv;
        }
        *(bf16x8*)(&s_h[pair][r][sub * 8]) = hv;
        // routing partial
        #pragma unroll
        for (int k = 0; k < 6; ++k) {
            float rv = (sub == 0) ? a[k] : 0.f;
            rv += __shfl_xor(rv, 4); rv += __shfl_xor(rv, 8);
            rv += __shfl_xor(rv, 16); rv += __shfl_xor(rv, 32);
            if (ln == 0) atomicAdd(rout_part + (blockIdx.x & 63) * 6 + k, rv);
        }
    }
    __syncthreads();

    // ---- Phase B: OUT[16x512] = H[16x32] @ W3^T; column half per wave
    bf16x8 ha = *(const bf16x8*)(&s_h[pair][l15][lg * 8]);
    float gate = scal[2];
    int nf0 = h * 16;
    for (int nf = nf0; nf < nf0 + 16; ++nf) {
        int col = nf * 16 + l15;
        bf16x8 wb = *(const bf16x8*)(w3p + col * 32 + lg * 8);
        f32x4 z = {0.f, 0.f, 0.f, 0.f};
        f32x4 d = __builtin_amdgcn_mfma_f32_16x16x32_bf16(ha, wb, z, 0, 0, 0);
        float bias = s_cob[col];
        float rsd = s_sd[col];
        #pragma unroll
        for (int rg = 0; rg < 4; ++rg) {
            size_t idx = (size_t)(wrow + lg * 4 + rg) * 512 + col;
            out[idx] = x[idx] + gate * ((d[rg] + bias) * rsd);
        }
    }
}

// ---------------- latent loss ----------------
__global__ void k5(const float* __restrict__ rp, float* __restrict__ out_latent) {
    __shared__ float sv[6];
    int t = threadIdx.x;
    if (t < 6) {
        float s = 0.f;
        for (int i = 0; i < 64; ++i) s += rp[i * 6 + t];
        sv[t] = s;
    }
    __syncthreads();
    if (t == 0) {
        float s = 0.f;
        for (int k = 0; k < 6; ++k) {
            float av = sv[k] * (1.f / (float)M_DIM) - (1.f / 6.f);
            s += av * av;
        }
        *out_latent = s / 6.f;
    }
}

extern "C" void kernel_launch(void* const* d_in, const int* in_sizes, int n_in,
                              void* d_out, int out_size, void* d_ws, size_t ws_size,
                              hipStream_t stream) {
    const float* x      = (const float*)d_in[0];
    const float* proj_w = (const float*)d_in[1];
    const float* proj_b = (const float*)d_in[2];
    const float* ln_g   = (const float*)d_in[3];
    const float* ln_b   = (const float*)d_in[4];
    const float* cent   = (const float*)d_in[5];
    const float* ciw    = (const float*)d_in[6];
    const float* cib    = (const float*)d_in[7];
    const float* cow    = (const float*)d_in[8];
    const float* cob    = (const float*)d_in[9];
    const float* ga     = (const float*)d_in[10];
    const float* rlt    = (const float*)d_in[11];
    const float* sev    = (const float*)d_in[12];

    // ws layout (~520 KB)
    char* ws = (char*)d_ws;
    float*  rout = (float*)(ws + 0);          // 64*6 f32
    float*  kn   = (float*)(ws + 2048);       // 192 f32
    float*  cwv  = (float*)(ws + 4096);       // 192 f32
    float*  scal = (float*)(ws + 6144);       // 3 f32
    __bf16* bpa  = (__bf16*)(ws + 8192);      // 64*512 bf16 (64 KB)
    __bf16* bpl  = (__bf16*)(ws + 73728);     // 32*512 bf16 (32 KB)
    __bf16* w3p  = (__bf16*)(ws + 106496);    // 512*32 bf16 (32 KB)
    float*  mean = (float*)(ws + 139264);     // 64*512 f32 (128 KB)
    float*  istd = (float*)(ws + 270336);     // 128 KB
    float*  stdv = (float*)(ws + 401408);     // 128 KB

    // outputs: FLOAT32, concatenated flat
    float* outp   = (float*)d_out;
    float* ustd   = outp + (size_t)M_DIM * D_DIM;
    float* ortho  = ustd + M_DIM;
    float* latent = ortho + 1;

    // stats scratch (8 MB) in d_out region; consumed before mega overwrites it
    float* part = (float*)d_out;

    hipMemsetAsync(rout, 0, 64 * 6 * sizeof(float), stream);
    k_pack<<<194, 256, 0, stream>>>(proj_w, ciw, cow, cent, ga, rlt, sev,
                                    bpa, bpl, w3p, kn, cwv, scal, ortho);
    k_stat1<<<2048, 128, 0, stream>>>(x, part);
    k_stat2<<<64, 512, 0, stream>>>(part, mean, istd, stdv);
    mega<<<2048, 256, 0, stream>>>(x, proj_b, ln_g, ln_b, cib, cob,
                                   mean, istd, stdv, kn, cwv, scal,
                                   bpa, bpl, w3p, outp, ustd, rout);
    k5<<<1, 64, 0, stream>>>(rout, latent);
}

// Round 6
// 147.848 us; speedup vs baseline: 1.3086x; 1.3086x over previous
//
#include <hip/hip_runtime.h>
#include <cstdint>
#include <cstddef>

#define N_DIM 1024
#define D_DIM 512
#define M_DIM 65536
#define NC 6

typedef float f32x4 __attribute__((ext_vector_type(4)));
typedef __bf16 bf16x8 __attribute__((ext_vector_type(8)));

__device__ __forceinline__ float sp_f(float z) {
    return z > 20.f ? z : log1pf(expf(z));
}

// ---------------- pack: bf16 weights, folded CW, normalized centroids, scalars,
// ---------------- + ortho loss (block 193) ----------------
__global__ void k_pack(const float* __restrict__ pw, const float* __restrict__ ciw,
                       const float* __restrict__ cow, const float* __restrict__ cent,
                       const float* __restrict__ ga, const float* __restrict__ rlt,
                       const float* __restrict__ sev,
                       __bf16* __restrict__ bpa, __bf16* __restrict__ bpl,
                       __bf16* __restrict__ w3p,
                       float* __restrict__ kn, float* __restrict__ cw,
                       float* __restrict__ scal, float* __restrict__ out_ortho) {
    __shared__ float skn[NC * 32];
    __shared__ float ssq[36];
    int bid = blockIdx.x, tid = threadIdx.x;
    if (bid < 128) {
        int i = bid * 256 + tid;          // 0..32767
        int c = i >> 9, k = i & 511;
        float w = (c < 32) ? pw[c * 512 + k] : ciw[(c - 32) * 544 + k];
        __bf16 hi = (__bf16)w;
        bpa[i] = hi;
        if (c < 32) bpl[i] = (__bf16)(w - (float)hi);
    } else if (bid < 192) {
        int j = (bid - 128) * 256 + tid;  // 0..16383
        w3p[j] = (__bf16)cow[j];
    } else if (bid == 192) {
        if (tid < 192) {                  // CW[k][h] = sum_p cent[k][p]*ciw[h][512+p]
            int k = tid >> 5, h = tid & 31;
            float s = 0.f;
            for (int p = 0; p < 32; ++p) s += cent[k * 32 + p] * ciw[h * 544 + 512 + p];
            cw[k * 32 + h] = s;
        } else if (tid < 192 + NC) {
            int k = tid - 192;
            float s = 0.f;
            for (int p = 0; p < 32; ++p) { float v = cent[k * 32 + p]; s += v * v; }
            float inv = 1.f / fmaxf(sqrtf(s), 1e-12f);
            for (int p = 0; p < 32; ++p) kn[k * 32 + p] = cent[k * 32 + p] * inv;
        } else if (tid == 198) {
            scal[0] = expf(rlt[0]);
            scal[1] = sp_f(sev[0]);
            scal[2] = 1.f / (1.f + expf(-ga[0]));
        }
    } else { // bid == 193: ortho loss
        if (tid < NC) {
            float s = 0.f;
            for (int p = 0; p < 32; ++p) { float v = cent[tid * 32 + p]; s += v * v; }
            float inv = 1.f / fmaxf(sqrtf(s), 1e-12f);
            for (int p = 0; p < 32; ++p) skn[tid * 32 + p] = cent[tid * 32 + p] * inv;
        }
        __syncthreads();
        if (tid < 36) {
            int i = tid / 6, j = tid % 6;
            float g = 0.f;
            for (int p = 0; p < 32; ++p) g += skn[i * 32 + p] * skn[j * 32 + p];
            float d = g - (i == j ? 1.f : 0.f);
            ssq[tid] = d * d;
        }
        __syncthreads();
        if (tid == 0) {
            float s = 0.f;
            for (int i = 0; i < 36; ++i) s += ssq[i];
            *out_ortho = s / 36.f;
        }
    }
}

// ---------------- stats pass 1: float4 partials ----------------
// grid 2048 x 128 threads; block = 32 rows x 512 cols
__global__ void k_stat1(const float* __restrict__ x, float* __restrict__ part) {
    int bid = blockIdx.x;
    int b = bid >> 5, sub = bid & 31;
    int d4 = threadIdx.x * 4;
    const float* px = x + ((size_t)(b * 1024 + sub * 32)) * 512 + d4;
    f32x4 s = {0.f, 0.f, 0.f, 0.f}, q = s;
    #pragma unroll 4
    for (int i = 0; i < 32; ++i) {
        float4 v = *(const float4*)(px + (size_t)i * 512);
        s.x += v.x; s.y += v.y; s.z += v.z; s.w += v.w;
        q.x += v.x * v.x; q.y += v.y * v.y; q.z += v.z * v.z; q.w += v.w * v.w;
    }
    *(f32x4*)(part + (size_t)bid * 512 + d4) = s;
    *(f32x4*)(part + (size_t)(2048 + bid) * 512 + d4) = q;
}

// ---------------- stats pass 2 ----------------
__global__ void k_stat2(const float* __restrict__ part, float* __restrict__ mean,
                        float* __restrict__ istd, float* __restrict__ stdv) {
    int b = blockIdx.x, d = threadIdx.x;
    float s = 0.f, q = 0.f;
    for (int c = 0; c < 32; ++c) {
        s += part[(size_t)(b * 32 + c) * 512 + d];
        q += part[(size_t)(2048 + b * 32 + c) * 512 + d];
    }
    float mu = s * (1.f / (float)N_DIM);
    float var = fmaxf((q - s * mu) * (1.f / (float)(N_DIM - 1)), 0.f);
    float sd = sqrtf(var) + 1e-5f;
    mean[b * D_DIM + d] = mu;
    istd[b * D_DIM + d] = 1.f / sd;
    stdv[b * D_DIM + d] = sd;
}

// ---------------- MEGA: split-K wave pairs, 32 rows/block ----------------
__launch_bounds__(256)
__global__ void mega(const float* __restrict__ x,
                     const float* __restrict__ proj_b, const float* __restrict__ ln_g,
                     const float* __restrict__ ln_b, const float* __restrict__ cib,
                     const float* __restrict__ cob,
                     const float* __restrict__ mean, const float* __restrict__ istd,
                     const float* __restrict__ stdv,
                     const float* __restrict__ kn, const float* __restrict__ cw,
                     const float* __restrict__ scal,
                     const __bf16* __restrict__ bpa, const __bf16* __restrict__ bpl,
                     const __bf16* __restrict__ w3p,
                     float* __restrict__ out, float* __restrict__ ustd_out,
                     float* __restrict__ rout_part) {
    __shared__ float s_mean[512];
    __shared__ float s_is[512];
    __shared__ float s_sd[512];
    __shared__ float s_cob[512];
    __shared__ __align__(16) float s_tile[2][16][68];
    __shared__ __align__(16) __bf16 s_h[2][16][40];

    int tid = threadIdx.x;
    int wv = tid >> 6, ln = tid & 63;
    int l15 = ln & 15, lg = ln >> 4;
    int pair = wv >> 1, h = wv & 1;

    int b = blockIdx.x >> 5;            // 32 blocks per batch entry
    int wrow = blockIdx.x * 32 + pair * 16;

    // stage per-b vectors in LDS
    if (tid < 128) {
        *(float4*)&s_mean[tid * 4] = *(const float4*)(mean + b * 512 + tid * 4);
        *(float4*)&s_sd[tid * 4]   = *(const float4*)(stdv + b * 512 + tid * 4);
    } else {
        int t = tid - 128;
        *(float4*)&s_is[t * 4]  = *(const float4*)(istd + b * 512 + t * 4);
        *(float4*)&s_cob[t * 4] = *(const float4*)(cob + t * 4);
    }
    __syncthreads();

    int kbase = h * 256;
    const float* xr = x + (size_t)(wrow + l15) * 512 + kbase;
    const __bf16* w0  = bpa + (size_t)l15 * 512 + kbase;
    const __bf16* w1  = bpa + (size_t)(16 + l15) * 512 + kbase;
    const __bf16* w2  = bpa + (size_t)(32 + l15) * 512 + kbase;
    const __bf16* w3  = bpa + (size_t)(48 + l15) * 512 + kbase;
    const __bf16* wl0 = bpl + (size_t)l15 * 512 + kbase;
    const __bf16* wl1 = bpl + (size_t)(16 + l15) * 512 + kbase;

    // ---- Phase A (half-K per wave): C[16x64] partial
    f32x4 a0 = {0.f, 0.f, 0.f, 0.f}, a1 = a0, a2 = a0, a3 = a0;
    #pragma unroll 4
    for (int ks = 0; ks < 8; ++ks) {
        int k0 = ks * 32 + lg * 8;
        int kk = kbase + k0;
        float4 xa = *(const float4*)(xr + k0);
        float4 xb = *(const float4*)(xr + k0 + 4);
        float4 ma = *(const float4*)&s_mean[kk];
        float4 m2 = *(const float4*)&s_mean[kk + 4];
        float4 ia = *(const float4*)&s_is[kk];
        float4 i2 = *(const float4*)&s_is[kk + 4];
        float xnf[8];
        xnf[0] = (xa.x - ma.x) * ia.x; xnf[1] = (xa.y - ma.y) * ia.y;
        xnf[2] = (xa.z - ma.z) * ia.z; xnf[3] = (xa.w - ma.w) * ia.w;
        xnf[4] = (xb.x - m2.x) * i2.x; xnf[5] = (xb.y - m2.y) * i2.y;
        xnf[6] = (xb.z - m2.z) * i2.z; xnf[7] = (xb.w - m2.w) * i2.w;
        bf16x8 ah, al;
        #pragma unroll
        for (int j = 0; j < 8; ++j) {
            __bf16 hh = (__bf16)xnf[j];
            ah[j] = hh;
            al[j] = (__bf16)(xnf[j] - (float)hh);
        }
        bf16x8 wh0 = *(const bf16x8*)(w0 + k0);
        bf16x8 wh1 = *(const bf16x8*)(w1 + k0);
        a0 = __builtin_amdgcn_mfma_f32_16x16x32_bf16(ah, wh0, a0, 0, 0, 0);
        a0 = __builtin_amdgcn_mfma_f32_16x16x32_bf16(ah, *(const bf16x8*)(wl0 + k0), a0, 0, 0, 0);
        a0 = __builtin_amdgcn_mfma_f32_16x16x32_bf16(al, wh0, a0, 0, 0, 0);
        a1 = __builtin_amdgcn_mfma_f32_16x16x32_bf16(ah, wh1, a1, 0, 0, 0);
        a1 = __builtin_amdgcn_mfma_f32_16x16x32_bf16(ah, *(const bf16x8*)(wl1 + k0), a1, 0, 0, 0);
        a1 = __builtin_amdgcn_mfma_f32_16x16x32_bf16(al, wh1, a1, 0, 0, 0);
        a2 = __builtin_amdgcn_mfma_f32_16x16x32_bf16(ah, *(const bf16x8*)(w2 + k0), a2, 0, 0, 0);
        a3 = __builtin_amdgcn_mfma_f32_16x16x32_bf16(ah, *(const bf16x8*)(w3 + k0), a3, 0, 0, 0);
    }

    // h=1 publishes partials
    if (h == 1) {
        #pragma unroll
        for (int rg = 0; rg < 4; ++rg) {
            int row = lg * 4 + rg;
            s_tile[pair][row][l15]      = a0[rg];
            s_tile[pair][row][16 + l15] = a1[rg];
            s_tile[pair][row][32 + l15] = a2[rg];
            s_tile[pair][row][48 + l15] = a3[rg];
        }
    }
    __syncthreads();

    // h=0 combines and runs row ops (same-wave DS ordering covers write->read)
    if (h == 0) {
        #pragma unroll
        for (int rg = 0; rg < 4; ++rg) {
            int row = lg * 4 + rg;
            s_tile[pair][row][l15]      += a0[rg];
            s_tile[pair][row][16 + l15] += a1[rg];
            s_tile[pair][row][32 + l15] += a2[rg];
            s_tile[pair][row][48 + l15] += a3[rg];
        }

        int r = ln >> 2, sub = ln & 3;
        const float* tr = &s_tile[pair][r][0];
        float4 t0 = *(const float4*)(tr + sub * 8);
        float4 t1 = *(const float4*)(tr + sub * 8 + 4);
        float4 pb0 = *(const float4*)(proj_b + sub * 8);
        float4 pb1 = *(const float4*)(proj_b + sub * 8 + 4);
        float P[8];
        P[0] = t0.x + pb0.x; P[1] = t0.y + pb0.y; P[2] = t0.z + pb0.z; P[3] = t0.w + pb0.w;
        P[4] = t1.x + pb1.x; P[5] = t1.y + pb1.y; P[6] = t1.z + pb1.z; P[7] = t1.w + pb1.w;
        float m = 0.f;
        #pragma unroll
        for (int j = 0; j < 8; ++j) m += P[j];
        m += __shfl_xor(m, 1); m += __shfl_xor(m, 2);
        float mu = m * (1.f / 32.f);
        float v = 0.f;
        #pragma unroll
        for (int j = 0; j < 8; ++j) { float d = P[j] - mu; v += d * d; }
        v += __shfl_xor(v, 1); v += __shfl_xor(v, 2);
        float rs = rsqrtf(v * (1.f / 32.f) + 1e-5f);
        float4 g0 = *(const float4*)(ln_g + sub * 8);
        float4 g1 = *(const float4*)(ln_g + sub * 8 + 4);
        float4 bl0 = *(const float4*)(ln_b + sub * 8);
        float4 bl1 = *(const float4*)(ln_b + sub * 8 + 4);
        float gg[8] = {g0.x, g0.y, g0.z, g0.w, g1.x, g1.y, g1.z, g1.w};
        float bb[8] = {bl0.x, bl0.y, bl0.z, bl0.w, bl1.x, bl1.y, bl1.z, bl1.w};
        float q[8]; float n2 = 0.f;
        #pragma unroll
        for (int j = 0; j < 8; ++j) {
            q[j] = (P[j] - mu) * rs * gg[j] + bb[j];
            n2 += q[j] * q[j];
        }
        n2 += __shfl_xor(n2, 1); n2 += __shfl_xor(n2, 2);
        float inv = 1.f / fmaxf(sqrtf(n2), 1e-12f);
        float sim[6];
        #pragma unroll
        for (int k = 0; k < 6; ++k) {
            const float* kr = kn + k * 32 + sub * 8;
            float4 ka = *(const float4*)(kr);
            float4 kb = *(const float4*)(kr + 4);
            float s = q[0] * ka.x + q[1] * ka.y + q[2] * ka.z + q[3] * ka.w
                    + q[4] * kb.x + q[5] * kb.y + q[6] * kb.z + q[7] * kb.w;
            s += __shfl_xor(s, 1); s += __shfl_xor(s, 2);
            sim[k] = s * inv;
        }
        float T = scal[0], sevv = scal[1];
        float mx = sim[0];
        #pragma unroll
        for (int k = 1; k < 6; ++k) mx = fmaxf(mx, sim[k]);
        float e[6], es = 0.f;
        #pragma unroll
        for (int k = 0; k < 6; ++k) { e[k] = expf((sim[k] - mx) * T); es += e[k]; }
        float einv = 1.f / es;
        float a[6];
        #pragma unroll
        for (int k = 0; k < 6; ++k) a[k] = e[k] * einv;
        float msim = 0.f;
        #pragma unroll
        for (int k = 0; k < 6; ++k) msim += sim[k];
        msim *= (1.f / 6.f);
        float S = 6.f;
        #pragma unroll
        for (int k = 0; k < 6; ++k) S += sevv * sp_f((sim[k] - msim) * 5.f);
        if (sub == 0) ustd_out[wrow + r] = 6.f / S;
        // h = gelu(corr_pre + cib + sum_k a_k*CW[k][:])
        float4 h0 = *(const float4*)(tr + 32 + sub * 8);
        float4 h1 = *(const float4*)(tr + 32 + sub * 8 + 4);
        float4 c0 = *(const float4*)(cib + sub * 8);
        float4 c1 = *(const float4*)(cib + sub * 8 + 4);
        float vh[8] = {h0.x + c0.x, h0.y + c0.y, h0.z + c0.z, h0.w + c0.w,
                       h1.x + c1.x, h1.y + c1.y, h1.z + c1.z, h1.w + c1.w};
        #pragma unroll
        for (int k = 0; k < 6; ++k) {
            const float* cr = cw + k * 32 + sub * 8;
            float4 ca = *(const float4*)(cr);
            float4 cb = *(const float4*)(cr + 4);
            vh[0] += a[k] * ca.x; vh[1] += a[k] * ca.y; vh[2] += a[k] * ca.z; vh[3] += a[k] * ca.w;
            vh[4] += a[k] * cb.x; vh[5] += a[k] * cb.y; vh[6] += a[k] * cb.z; vh[7] += a[k] * cb.w;
        }
        bf16x8 hv;
        #pragma unroll
        for (int j = 0; j < 8; ++j) {
            float gv = 0.5f * vh[j] * (1.f + erff(vh[j] * 0.70710678118654752f));
            hv[j] = (__bf16)gv;
        }
        *(bf16x8*)(&s_h[pair][r][sub * 8]) = hv;
        // routing partial
        #pragma unroll
        for (int k = 0; k < 6; ++k) {
            float rv = (sub == 0) ? a[k] : 0.f;
            rv += __shfl_xor(rv, 4); rv += __shfl_xor(rv, 8);
            rv += __shfl_xor(rv, 16); rv += __shfl_xor(rv, 32);
            if (ln == 0) atomicAdd(rout_part + (blockIdx.x & 63) * 6 + k, rv);
        }
    }
    __syncthreads();

    // ---- Phase B: OUT[16x512] = H[16x32] @ W3^T; column half per wave
    bf16x8 ha = *(const bf16x8*)(&s_h[pair][l15][lg * 8]);
    float gate = scal[2];
    int nf0 = h * 16;
    for (int nf = nf0; nf < nf0 + 16; ++nf) {
        int col = nf * 16 + l15;
        bf16x8 wb = *(const bf16x8*)(w3p + col * 32 + lg * 8);
        f32x4 z = {0.f, 0.f, 0.f, 0.f};
        f32x4 d = __builtin_amdgcn_mfma_f32_16x16x32_bf16(ha, wb, z, 0, 0, 0);
        float bias = s_cob[col];
        float rsd = s_sd[col];
        #pragma unroll
        for (int rg = 0; rg < 4; ++rg) {
            size_t idx = (size_t)(wrow + lg * 4 + rg) * 512 + col;
            out[idx] = x[idx] + gate * ((d[rg] + bias) * rsd);
        }
    }
}

// ---------------- latent loss ----------------
__global__ void k5(const float* __restrict__ rp, float* __restrict__ out_latent) {
    __shared__ float sv[6];
    int t = threadIdx.x;
    if (t < 6) {
        float s = 0.f;
        for (int i = 0; i < 64; ++i) s += rp[i * 6 + t];
        sv[t] = s;
    }
    __syncthreads();
    if (t == 0) {
        float s = 0.f;
        for (int k = 0; k < 6; ++k) {
            float av = sv[k] * (1.f / (float)M_DIM) - (1.f / 6.f);
            s += av * av;
        }
        *out_latent = s / 6.f;
    }
}

extern "C" void kernel_launch(void* const* d_in, const int* in_sizes, int n_in,
                              void* d_out, int out_size, void* d_ws, size_t ws_size,
                              hipStream_t stream) {
    const float* x      = (const float*)d_in[0];
    const float* proj_w = (const float*)d_in[1];
    const float* proj_b = (const float*)d_in[2];
    const float* ln_g   = (const float*)d_in[3];
    const float* ln_b   = (const float*)d_in[4];
    const float* cent   = (const float*)d_in[5];
    const float* ciw    = (const float*)d_in[6];
    const float* cib    = (const float*)d_in[7];
    const float* cow    = (const float*)d_in[8];
    const float* cob    = (const float*)d_in[9];
    const float* ga     = (const float*)d_in[10];
    const float* rlt    = (const float*)d_in[11];
    const float* sev    = (const float*)d_in[12];

    // ws layout (~520 KB)
    char* ws = (char*)d_ws;
    float*  rout = (float*)(ws + 0);          // 64*6 f32
    float*  kn   = (float*)(ws + 2048);       // 192 f32
    float*  cwv  = (float*)(ws + 4096);       // 192 f32
    float*  scal = (float*)(ws + 6144);       // 3 f32
    __bf16* bpa  = (__bf16*)(ws + 8192);      // 64*512 bf16 (64 KB)
    __bf16* bpl  = (__bf16*)(ws + 73728);     // 32*512 bf16 (32 KB)
    __bf16* w3p  = (__bf16*)(ws + 106496);    // 512*32 bf16 (32 KB)
    float*  mean = (float*)(ws + 139264);     // 64*512 f32 (128 KB)
    float*  istd = (float*)(ws + 270336);     // 128 KB
    float*  stdv = (float*)(ws + 401408);     // 128 KB

    // outputs: FLOAT32, concatenated flat
    float* outp   = (float*)d_out;
    float* ustd   = outp + (size_t)M_DIM * D_DIM;
    float* ortho  = ustd + M_DIM;
    float* latent = ortho + 1;

    // stats scratch (8 MB) in d_out region; consumed before mega overwrites it
    float* part = (float*)d_out;

    hipMemsetAsync(rout, 0, 64 * 6 * sizeof(float), stream);
    k_pack<<<194, 256, 0, stream>>>(proj_w, ciw, cow, cent, ga, rlt, sev,
                                    bpa, bpl, w3p, kn, cwv, scal, ortho);
    k_stat1<<<2048, 128, 0, stream>>>(x, part);
    k_stat2<<<64, 512, 0, stream>>>(part, mean, istd, stdv);
    mega<<<2048, 256, 0, stream>>>(x, proj_b, ln_g, ln_b, cib, cob,
                                   mean, istd, stdv, kn, cwv, scal,
                                   bpa, bpl, w3p, outp, ustd, rout);
    k5<<<1, 64, 0, stream>>>(rout, latent);
}

// Round 7
// 140.260 us; speedup vs baseline: 1.3794x; 1.0541x over previous
//
#include <hip/hip_runtime.h>
#include <cstdint>
#include <cstddef>

#define N_DIM 1024
#define D_DIM 512
#define M_DIM 65536
#define NC 6

typedef float f32x4 __attribute__((ext_vector_type(4)));
typedef __bf16 bf16x8 __attribute__((ext_vector_type(8)));

__device__ __forceinline__ float sp_f(float z) {
    return z > 20.f ? z : log1pf(expf(z));
}

// ---------------- pack: bf16 weights, folded CW, normalized centroids, scalars,
// ---------------- + ortho loss (block 193) ----------------
__global__ void k_pack(const float* __restrict__ pw, const float* __restrict__ ciw,
                       const float* __restrict__ cow, const float* __restrict__ cent,
                       const float* __restrict__ ga, const float* __restrict__ rlt,
                       const float* __restrict__ sev,
                       __bf16* __restrict__ bpa, __bf16* __restrict__ bpl,
                       __bf16* __restrict__ w3p,
                       float* __restrict__ kn, float* __restrict__ cw,
                       float* __restrict__ scal, float* __restrict__ out_ortho) {
    __shared__ float skn[NC * 32];
    __shared__ float ssq[36];
    int bid = blockIdx.x, tid = threadIdx.x;
    if (bid < 128) {
        int i = bid * 256 + tid;          // 0..32767
        int c = i >> 9, k = i & 511;
        float w = (c < 32) ? pw[c * 512 + k] : ciw[(c - 32) * 544 + k];
        __bf16 hi = (__bf16)w;
        bpa[i] = hi;
        if (c < 32) bpl[i] = (__bf16)(w - (float)hi);
    } else if (bid < 192) {
        int j = (bid - 128) * 256 + tid;  // 0..16383
        w3p[j] = (__bf16)cow[j];
    } else if (bid == 192) {
        if (tid < 192) {                  // CW[k][h] = sum_p cent[k][p]*ciw[h][512+p]
            int k = tid >> 5, h = tid & 31;
            float s = 0.f;
            for (int p = 0; p < 32; ++p) s += cent[k * 32 + p] * ciw[h * 544 + 512 + p];
            cw[k * 32 + h] = s;
        } else if (tid < 192 + NC) {
            int k = tid - 192;
            float s = 0.f;
            for (int p = 0; p < 32; ++p) { float v = cent[k * 32 + p]; s += v * v; }
            float inv = 1.f / fmaxf(sqrtf(s), 1e-12f);
            for (int p = 0; p < 32; ++p) kn[k * 32 + p] = cent[k * 32 + p] * inv;
        } else if (tid == 198) {
            scal[0] = expf(rlt[0]);
            scal[1] = sp_f(sev[0]);
            scal[2] = 1.f / (1.f + expf(-ga[0]));
        }
    } else { // bid == 193: ortho loss
        if (tid < NC) {
            float s = 0.f;
            for (int p = 0; p < 32; ++p) { float v = cent[tid * 32 + p]; s += v * v; }
            float inv = 1.f / fmaxf(sqrtf(s), 1e-12f);
            for (int p = 0; p < 32; ++p) skn[tid * 32 + p] = cent[tid * 32 + p] * inv;
        }
        __syncthreads();
        if (tid < 36) {
            int i = tid / 6, j = tid % 6;
            float g = 0.f;
            for (int p = 0; p < 32; ++p) g += skn[i * 32 + p] * skn[j * 32 + p];
            float d = g - (i == j ? 1.f : 0.f);
            ssq[tid] = d * d;
        }
        __syncthreads();
        if (tid == 0) {
            float s = 0.f;
            for (int i = 0; i < 36; ++i) s += ssq[i];
            *out_ortho = s / 36.f;
        }
    }
}

// ---------------- stats pass 1: float4 partials ----------------
__global__ void k_stat1(const float* __restrict__ x, float* __restrict__ part) {
    int bid = blockIdx.x;
    int b = bid >> 5, sub = bid & 31;
    int d4 = threadIdx.x * 4;
    const float* px = x + ((size_t)(b * 1024 + sub * 32)) * 512 + d4;
    f32x4 s = {0.f, 0.f, 0.f, 0.f}, q = s;
    #pragma unroll 8
    for (int i = 0; i < 32; ++i) {
        float4 v = *(const float4*)(px + (size_t)i * 512);
        s.x += v.x; s.y += v.y; s.z += v.z; s.w += v.w;
        q.x += v.x * v.x; q.y += v.y * v.y; q.z += v.z * v.z; q.w += v.w * v.w;
    }
    *(f32x4*)(part + (size_t)bid * 512 + d4) = s;
    *(f32x4*)(part + (size_t)(2048 + bid) * 512 + d4) = q;
}

// ---------------- stats pass 2 ----------------
__global__ void k_stat2(const float* __restrict__ part, float* __restrict__ mean,
                        float* __restrict__ istd, float* __restrict__ stdv) {
    int b = blockIdx.x, d = threadIdx.x;
    float s = 0.f, q = 0.f;
    for (int c = 0; c < 32; ++c) {
        s += part[(size_t)(b * 32 + c) * 512 + d];
        q += part[(size_t)(2048 + b * 32 + c) * 512 + d];
    }
    float mu = s * (1.f / (float)N_DIM);
    float var = fmaxf((q - s * mu) * (1.f / (float)(N_DIM - 1)), 0.f);
    float sd = sqrtf(var) + 1e-5f;
    mean[b * D_DIM + d] = mu;
    istd[b * D_DIM + d] = 1.f / sd;
    stdv[b * D_DIM + d] = sd;
}

// ---------------- MEGA: split-K wave pairs, 32 rows/block ----------------
__launch_bounds__(256)
__global__ void mega(const float* __restrict__ x,
                     const float* __restrict__ proj_b, const float* __restrict__ ln_g,
                     const float* __restrict__ ln_b, const float* __restrict__ cib,
                     const float* __restrict__ cob,
                     const float* __restrict__ mean, const float* __restrict__ istd,
                     const float* __restrict__ stdv,
                     const float* __restrict__ kn, const float* __restrict__ cw,
                     const float* __restrict__ scal,
                     const __bf16* __restrict__ bpa, const __bf16* __restrict__ bpl,
                     const __bf16* __restrict__ w3p,
                     float* __restrict__ out, float* __restrict__ ustd_out,
                     float* __restrict__ rout_part) {
    __shared__ float s_mean[512];
    __shared__ float s_is[512];
    __shared__ float s_sd[512];
    __shared__ float s_cob[512];
    __shared__ __align__(16) float s_tile[2][16][68];
    __shared__ __align__(16) __bf16 s_h[2][16][40];

    int tid = threadIdx.x;
    int wv = tid >> 6, ln = tid & 63;
    int l15 = ln & 15, lg = ln >> 4;
    int pair = wv >> 1, h = wv & 1;

    int b = blockIdx.x >> 5;            // 32 blocks per batch entry
    int wrow = blockIdx.x * 32 + pair * 16;

    // stage per-b vectors in LDS
    if (tid < 128) {
        *(float4*)&s_mean[tid * 4] = *(const float4*)(mean + b * 512 + tid * 4);
        *(float4*)&s_sd[tid * 4]   = *(const float4*)(stdv + b * 512 + tid * 4);
    } else {
        int t = tid - 128;
        *(float4*)&s_is[t * 4]  = *(const float4*)(istd + b * 512 + t * 4);
        *(float4*)&s_cob[t * 4] = *(const float4*)(cob + t * 4);
    }
    __syncthreads();

    int kbase = h * 256;
    const float* xr = x + (size_t)(wrow + l15) * 512 + kbase;
    const __bf16* w0  = bpa + (size_t)l15 * 512 + kbase;
    const __bf16* w1  = bpa + (size_t)(16 + l15) * 512 + kbase;
    const __bf16* w2  = bpa + (size_t)(32 + l15) * 512 + kbase;
    const __bf16* w3  = bpa + (size_t)(48 + l15) * 512 + kbase;
    const __bf16* wl0 = bpl + (size_t)l15 * 512 + kbase;
    const __bf16* wl1 = bpl + (size_t)(16 + l15) * 512 + kbase;

    // ---- Phase A (half-K per wave): C[16x64] partial
    f32x4 a0 = {0.f, 0.f, 0.f, 0.f}, a1 = a0, a2 = a0, a3 = a0;
    #pragma unroll
    for (int ks = 0; ks < 8; ++ks) {
        int k0 = ks * 32 + lg * 8;
        int kk = kbase + k0;
        float4 xa = *(const float4*)(xr + k0);
        float4 xb = *(const float4*)(xr + k0 + 4);
        float4 ma = *(const float4*)&s_mean[kk];
        float4 m2 = *(const float4*)&s_mean[kk + 4];
        float4 ia = *(const float4*)&s_is[kk];
        float4 i2 = *(const float4*)&s_is[kk + 4];
        float xnf[8];
        xnf[0] = (xa.x - ma.x) * ia.x; xnf[1] = (xa.y - ma.y) * ia.y;
        xnf[2] = (xa.z - ma.z) * ia.z; xnf[3] = (xa.w - ma.w) * ia.w;
        xnf[4] = (xb.x - m2.x) * i2.x; xnf[5] = (xb.y - m2.y) * i2.y;
        xnf[6] = (xb.z - m2.z) * i2.z; xnf[7] = (xb.w - m2.w) * i2.w;
        bf16x8 ah, al;
        #pragma unroll
        for (int j = 0; j < 8; ++j) {
            __bf16 hh = (__bf16)xnf[j];
            ah[j] = hh;
            al[j] = (__bf16)(xnf[j] - (float)hh);
        }
        bf16x8 wh0 = *(const bf16x8*)(w0 + k0);
        bf16x8 wh1 = *(const bf16x8*)(w1 + k0);
        a0 = __builtin_amdgcn_mfma_f32_16x16x32_bf16(ah, wh0, a0, 0, 0, 0);
        a0 = __builtin_amdgcn_mfma_f32_16x16x32_bf16(ah, *(const bf16x8*)(wl0 + k0), a0, 0, 0, 0);
        a0 = __builtin_amdgcn_mfma_f32_16x16x32_bf16(al, wh0, a0, 0, 0, 0);
        a1 = __builtin_amdgcn_mfma_f32_16x16x32_bf16(ah, wh1, a1, 0, 0, 0);
        a1 = __builtin_amdgcn_mfma_f32_16x16x32_bf16(ah, *(const bf16x8*)(wl1 + k0), a1, 0, 0, 0);
        a1 = __builtin_amdgcn_mfma_f32_16x16x32_bf16(al, wh1, a1, 0, 0, 0);
        a2 = __builtin_amdgcn_mfma_f32_16x16x32_bf16(ah, *(const bf16x8*)(w2 + k0), a2, 0, 0, 0);
        a3 = __builtin_amdgcn_mfma_f32_16x16x32_bf16(ah, *(const bf16x8*)(w3 + k0), a3, 0, 0, 0);
    }

    // h=1 publishes partials
    if (h == 1) {
        #pragma unroll
        for (int rg = 0; rg < 4; ++rg) {
            int row = lg * 4 + rg;
            s_tile[pair][row][l15]      = a0[rg];
            s_tile[pair][row][16 + l15] = a1[rg];
            s_tile[pair][row][32 + l15] = a2[rg];
            s_tile[pair][row][48 + l15] = a3[rg];
        }
    }
    __syncthreads();

    // h=0 combines and runs row ops
    if (h == 0) {
        #pragma unroll
        for (int rg = 0; rg < 4; ++rg) {
            int row = lg * 4 + rg;
            s_tile[pair][row][l15]      += a0[rg];
            s_tile[pair][row][16 + l15] += a1[rg];
            s_tile[pair][row][32 + l15] += a2[rg];
            s_tile[pair][row][48 + l15] += a3[rg];
        }

        int r = ln >> 2, sub = ln & 3;
        const float* tr = &s_tile[pair][r][0];
        float4 t0 = *(const float4*)(tr + sub * 8);
        float4 t1 = *(const float4*)(tr + sub * 8 + 4);
        float4 pb0 = *(const float4*)(proj_b + sub * 8);
        float4 pb1 = *(const float4*)(proj_b + sub * 8 + 4);
        float P[8];
        P[0] = t0.x + pb0.x; P[1] = t0.y + pb0.y; P[2] = t0.z + pb0.z; P[3] = t0.w + pb0.w;
        P[4] = t1.x + pb1.x; P[5] = t1.y + pb1.y; P[6] = t1.z + pb1.z; P[7] = t1.w + pb1.w;
        float m = 0.f;
        #pragma unroll
        for (int j = 0; j < 8; ++j) m += P[j];
        m += __shfl_xor(m, 1); m += __shfl_xor(m, 2);
        float mu = m * (1.f / 32.f);
        float v = 0.f;
        #pragma unroll
        for (int j = 0; j < 8; ++j) { float d = P[j] - mu; v += d * d; }
        v += __shfl_xor(v, 1); v += __shfl_xor(v, 2);
        float rs = rsqrtf(v * (1.f / 32.f) + 1e-5f);
        float4 g0 = *(const float4*)(ln_g + sub * 8);
        float4 g1 = *(const float4*)(ln_g + sub * 8 + 4);
        float4 bl0 = *(const float4*)(ln_b + sub * 8);
        float4 bl1 = *(const float4*)(ln_b + sub * 8 + 4);
        float gg[8] = {g0.x, g0.y, g0.z, g0.w, g1.x, g1.y, g1.z, g1.w};
        float bb[8] = {bl0.x, bl0.y, bl0.z, bl0.w, bl1.x, bl1.y, bl1.z, bl1.w};
        float q[8]; float n2 = 0.f;
        #pragma unroll
        for (int j = 0; j < 8; ++j) {
            q[j] = (P[j] - mu) * rs * gg[j] + bb[j];
            n2 += q[j] * q[j];
        }
        n2 += __shfl_xor(n2, 1); n2 += __shfl_xor(n2, 2);
        float inv = 1.f / fmaxf(sqrtf(n2), 1e-12f);
        float sim[6];
        #pragma unroll
        for (int k = 0; k < 6; ++k) {
            const float* kr = kn + k * 32 + sub * 8;
            float4 ka = *(const float4*)(kr);
            float4 kb = *(const float4*)(kr + 4);
            float s = q[0] * ka.x + q[1] * ka.y + q[2] * ka.z + q[3] * ka.w
                    + q[4] * kb.x + q[5] * kb.y + q[6] * kb.z + q[7] * kb.w;
            s += __shfl_xor(s, 1); s += __shfl_xor(s, 2);
            sim[k] = s * inv;
        }
        float T = scal[0], sevv = scal[1];
        float mx = sim[0];
        #pragma unroll
        for (int k = 1; k < 6; ++k) mx = fmaxf(mx, sim[k]);
        float e[6], es = 0.f;
        #pragma unroll
        for (int k = 0; k < 6; ++k) { e[k] = expf((sim[k] - mx) * T); es += e[k]; }
        float einv = 1.f / es;
        float a[6];
        #pragma unroll
        for (int k = 0; k < 6; ++k) a[k] = e[k] * einv;
        float msim = 0.f;
        #pragma unroll
        for (int k = 0; k < 6; ++k) msim += sim[k];
        msim *= (1.f / 6.f);
        float S = 6.f;
        #pragma unroll
        for (int k = 0; k < 6; ++k) S += sevv * sp_f((sim[k] - msim) * 5.f);
        if (sub == 0) ustd_out[wrow + r] = 6.f / S;
        // h = gelu(corr_pre + cib + sum_k a_k*CW[k][:])
        float4 h0 = *(const float4*)(tr + 32 + sub * 8);
        float4 h1 = *(const float4*)(tr + 32 + sub * 8 + 4);
        float4 c0 = *(const float4*)(cib + sub * 8);
        float4 c1 = *(const float4*)(cib + sub * 8 + 4);
        float vh[8] = {h0.x + c0.x, h0.y + c0.y, h0.z + c0.z, h0.w + c0.w,
                       h1.x + c1.x, h1.y + c1.y, h1.z + c1.z, h1.w + c1.w};
        #pragma unroll
        for (int k = 0; k < 6; ++k) {
            const float* cr = cw + k * 32 + sub * 8;
            float4 ca = *(const float4*)(cr);
            float4 cb = *(const float4*)(cr + 4);
            vh[0] += a[k] * ca.x; vh[1] += a[k] * ca.y; vh[2] += a[k] * ca.z; vh[3] += a[k] * ca.w;
            vh[4] += a[k] * cb.x; vh[5] += a[k] * cb.y; vh[6] += a[k] * cb.z; vh[7] += a[k] * cb.w;
        }
        bf16x8 hv;
        #pragma unroll
        for (int j = 0; j < 8; ++j) {
            float gv = 0.5f * vh[j] * (1.f + erff(vh[j] * 0.70710678118654752f));
            hv[j] = (__bf16)gv;
        }
        *(bf16x8*)(&s_h[pair][r][sub * 8]) = hv;
        // routing partial
        #pragma unroll
        for (int k = 0; k < 6; ++k) {
            float rv = (sub == 0) ? a[k] : 0.f;
            rv += __shfl_xor(rv, 4); rv += __shfl_xor(rv, 8);
            rv += __shfl_xor(rv, 16); rv += __shfl_xor(rv, 32);
            if (ln == 0) atomicAdd(rout_part + (blockIdx.x & 63) * 6 + k, rv);
        }
    }
    __syncthreads();

    // ---- Phase B (transposed MFMA): lane holds row=l15, 4 consecutive cols.
    // mfma(A=w3 frag, B=h frag) -> D^T: per-lane float4 contiguous epilogue.
    bf16x8 ha = *(const bf16x8*)(&s_h[pair][l15][lg * 8]);
    float gate = scal[2];
    int nf0 = h * 16;
    int row = wrow + l15;
    for (int nf = nf0; nf < nf0 + 16; ++nf) {
        int col = nf * 16 + l15;
        bf16x8 wb = *(const bf16x8*)(w3p + col * 32 + lg * 8);
        f32x4 z = {0.f, 0.f, 0.f, 0.f};
        f32x4 d = __builtin_amdgcn_mfma_f32_16x16x32_bf16(wb, ha, z, 0, 0, 0);
        int colb = nf * 16 + lg * 4;
        float4 xv = *(const float4*)(x + (size_t)row * 512 + colb);
        float4 bi = *(const float4*)&s_cob[colb];
        float4 sd = *(const float4*)&s_sd[colb];
        float4 o;
        o.x = xv.x + gate * ((d[0] + bi.x) * sd.x);
        o.y = xv.y + gate * ((d[1] + bi.y) * sd.y);
        o.z = xv.z + gate * ((d[2] + bi.z) * sd.z);
        o.w = xv.w + gate * ((d[3] + bi.w) * sd.w);
        *(float4*)(out + (size_t)row * 512 + colb) = o;
    }
}

// ---------------- latent loss ----------------
__global__ void k5(const float* __restrict__ rp, float* __restrict__ out_latent) {
    __shared__ float sv[6];
    int t = threadIdx.x;
    if (t < 6) {
        float s = 0.f;
        for (int i = 0; i < 64; ++i) s += rp[i * 6 + t];
        sv[t] = s;
    }
    __syncthreads();
    if (t == 0) {
        float s = 0.f;
        for (int k = 0; k < 6; ++k) {
            float av = sv[k] * (1.f / (float)M_DIM) - (1.f / 6.f);
            s += av * av;
        }
        *out_latent = s / 6.f;
    }
}

extern "C" void kernel_launch(void* const* d_in, const int* in_sizes, int n_in,
                              void* d_out, int out_size, void* d_ws, size_t ws_size,
                              hipStream_t stream) {
    const float* x      = (const float*)d_in[0];
    const float* proj_w = (const float*)d_in[1];
    const float* proj_b = (const float*)d_in[2];
    const float* ln_g   = (const float*)d_in[3];
    const float* ln_b   = (const float*)d_in[4];
    const float* cent   = (const float*)d_in[5];
    const float* ciw    = (const float*)d_in[6];
    const float* cib    = (const float*)d_in[7];
    const float* cow    = (const float*)d_in[8];
    const float* cob    = (const float*)d_in[9];
    const float* ga     = (const float*)d_in[10];
    const float* rlt    = (const float*)d_in[11];
    const float* sev    = (const float*)d_in[12];

    // ws layout (~520 KB)
    char* ws = (char*)d_ws;
    float*  rout = (float*)(ws + 0);          // 64*6 f32
    float*  kn   = (float*)(ws + 2048);       // 192 f32
    float*  cwv  = (float*)(ws + 4096);       // 192 f32
    float*  scal = (float*)(ws + 6144);       // 3 f32
    __bf16* bpa  = (__bf16*)(ws + 8192);      // 64*512 bf16 (64 KB)
    __bf16* bpl  = (__bf16*)(ws + 73728);     // 32*512 bf16 (32 KB)
    __bf16* w3p  = (__bf16*)(ws + 106496);    // 512*32 bf16 (32 KB)
    float*  mean = (float*)(ws + 139264);     // 64*512 f32 (128 KB)
    float*  istd = (float*)(ws + 270336);     // 128 KB
    float*  stdv = (float*)(ws + 401408);     // 128 KB

    // outputs: FLOAT32, concatenated flat
    float* outp   = (float*)d_out;
    float* ustd   = outp + (size_t)M_DIM * D_DIM;
    float* ortho  = ustd + M_DIM;
    float* latent = ortho + 1;

    // stats scratch (8 MB) in d_out region; consumed before mega overwrites it
    float* part = (float*)d_out;

    hipMemsetAsync(rout, 0, 64 * 6 * sizeof(float), stream);
    k_pack<<<194, 256, 0, stream>>>(proj_w, ciw, cow, cent, ga, rlt, sev,
                                    bpa, bpl, w3p, kn, cwv, scal, ortho);
    k_stat1<<<2048, 128, 0, stream>>>(x, part);
    k_stat2<<<64, 512, 0, stream>>>(part, mean, istd, stdv);
    mega<<<2048, 256, 0, stream>>>(x, proj_b, ln_g, ln_b, cib, cob,
                                   mean, istd, stdv, kn, cwv, scal,
                                   bpa, bpl, w3p, outp, ustd, rout);
    k5<<<1, 64, 0, stream>>>(rout, latent);
}